// Round 9
// baseline (111.667 us; speedup 1.0000x reference)
//
#include <hip/hip_runtime.h>
#include <hip/hip_bf16.h>

typedef unsigned short u16;
typedef unsigned int u32;
typedef __attribute__((ext_vector_type(8))) short short8;
typedef __attribute__((ext_vector_type(4))) float f32x4;

#define S_LEN 2048
#define D_DIM 1024
#define NH    16
#define DH    64
#define B_SZ  2
#define M_ROWS (B_SZ * S_LEN)   // 4096
#define NCHUNK (S_LEN / 64)     // 32 chunks of 64 rows

// ---------- helpers ----------
__device__ __forceinline__ u16 f2bf(float f) {
  u32 u = __float_as_uint(f);
  u += 0x7FFFu + ((u >> 16) & 1u);   // RNE
  return (u16)(u >> 16);
}
__device__ __forceinline__ float bf2f(u16 u) {
  return __uint_as_float(((u32)u) << 16);
}
__device__ __forceinline__ u32 pack_bf2(float lo, float hi) {
  __hip_bfloat162 p = __float22bfloat162_rn(make_float2(lo, hi));  // v_cvt_pk_bf16_f32
  u32 r;
  __builtin_memcpy(&r, &p, 4);
  return r;
}

__device__ __forceinline__ void gll16(const void* g, void* l) {
  __builtin_amdgcn_global_load_lds((const __attribute__((address_space(1))) u32*)g,
                                   (__attribute__((address_space(3))) u32*)l,
                                   16, 0, 0);
}

#define SP1() __builtin_amdgcn_s_setprio(1)
#define SP0() __builtin_amdgcn_s_setprio(0)
#define BAR() __builtin_amdgcn_s_barrier()
#define LGKM0() do { asm volatile("s_waitcnt lgkmcnt(0)" ::: "memory"); \
                     __builtin_amdgcn_sched_barrier(0); } while (0)

// ---------- fused prep: x->bf16, 5 weights->wcat bf16, rope table ----------
__global__ __launch_bounds__(256) void prep_kernel(
    const float* __restrict__ x,
    const float* __restrict__ wq, const float* __restrict__ wk,
    const float* __restrict__ wv, const float* __restrict__ wg,
    const float* __restrict__ wo,
    u16* __restrict__ xb, u16* __restrict__ wcat, float2* __restrict__ rope)
{
  const int bid = blockIdx.x, tid = threadIdx.x;
  if (bid < 4096) {                      // x: 4096*1024 elems / 4 = 1048576 float4
    const int i = bid * 256 + tid;
    const float4 v = ((const float4*)x)[i];
    u32* d = (u32*)xb;
    d[2 * i]     = (u32)f2bf(v.x) | ((u32)f2bf(v.y) << 16);
    d[2 * i + 1] = (u32)f2bf(v.z) | ((u32)f2bf(v.w) << 16);
  } else if (bid < 9216) {               // 5 weights, 1024 blocks each
    const int t = bid - 4096;
    const int seg = t >> 10;
    const float* src = seg == 0 ? wq : seg == 1 ? wk : seg == 2 ? wv : seg == 3 ? wg : wo;
    const int i = (t & 1023) * 256 + tid;
    const float4 v = ((const float4*)src)[i];
    u32* d = (u32*)(wcat + (size_t)seg * D_DIM * D_DIM);
    d[2 * i]     = (u32)f2bf(v.x) | ((u32)f2bf(v.y) << 16);
    d[2 * i + 1] = (u32)f2bf(v.z) | ((u32)f2bf(v.w) << 16);
  } else {                               // rope: S_LEN*32 entries, 256 blocks
    const int i = (bid - 9216) * 256 + tid;
    const int s = i >> 5, j = i & 31;
    float inv = exp2f(-(float)j * (13.287712379549449f / 32.f)); // 10000^(-j/32)
    float fr = (float)s * inv;
    rope[i] = make_float2(cosf(fr), sinf(fr));
  }
}

// ---------- ring-3 deep-pipelined 256x128 proj GEMM + fused epilogues ----------
// z = col>>10: 0=q(+rope,*0.125*gamma^(s&63)), 1=k(+rope,*gamma^-(s&63), +kT),
// 2=v(->vT transposed), 3=g(silu)
// 8 waves (4M x 2N), BK=64, ring-3 tile buffers for A and B (144 KB LDS),
// one barrier + one counted vmcnt(6) per K-step; tile t+2 staged at step t
// -> gate slack ~2 steps (covers L3 latency on the A-panel re-reads).
__global__ __launch_bounds__(512, 2) void proj_kernel(
    const u16* __restrict__ xb, const u16* __restrict__ wcat,
    u16* __restrict__ qb, u16* __restrict__ kb, u16* __restrict__ kT,
    u16* __restrict__ vT, u16* __restrict__ gb,
    const float2* __restrict__ rope)
{
  // A: 3 slots x 16384 u16 (256x64), B: 3 slots x 8192 u16 (128x64) = 144 KB
  __shared__ u16 lds[73728];
  const int tid = threadIdx.x, lane = tid & 63, wid = tid >> 6;
  const int wm = wid >> 1, wn = wid & 1;
  const int l15 = lane & 15, l4 = lane >> 4;

  const int bid = blockIdx.x;                     // 512 blocks, 512%8==0
  const int sw = (bid & 7) * 64 + (bid >> 3);     // XCD-bijective swizzle
  const int m0 = (sw & 15) * 256;
  const int n0 = (sw >> 4) * 128;

  f32x4 acc[4][4];
  #pragma unroll
  for (int m = 0; m < 4; ++m)
    #pragma unroll
    for (int n = 0; n < 4; ++n)
      acc[m][n] = (f32x4){0.f, 0.f, 0.f, 0.f};

  // stage full tiles (pre-swizzled global source + linear LDS, rule 21)
  auto stA = [&](int t) {                         // 256x64, 4 gll16/thread
    u16* dst = lds + (t % 3) * 16384;
    const u16* src = xb + (size_t)m0 * D_DIM + t * 64;
    #pragma unroll
    for (int j = 0; j < 4; ++j) {
      const int c = tid + j * 512, row = c >> 3, ch = c & 7;
      gll16(src + (size_t)row * D_DIM + ((ch ^ (row & 7)) << 3), dst + c * 8);
    }
  };
  auto stB = [&](int t) {                         // 128x64, 2 gll16/thread
    u16* dst = lds + 49152 + (t % 3) * 8192;
    const u16* src = wcat + (size_t)n0 * D_DIM + t * 64;
    #pragma unroll
    for (int j = 0; j < 2; ++j) {
      const int c = tid + j * 512, row = c >> 3, ch = c & 7;
      gll16(src + (size_t)row * D_DIM + ((ch ^ (row & 7)) << 3), dst + c * 8);
    }
  };

  // prologue: tiles 0,1 staged; wait tile 0 (oldest 6 of 12)
  stA(0); stB(0); stA(1); stB(1);
  asm volatile("s_waitcnt vmcnt(6)" ::: "memory");
  __builtin_amdgcn_sched_barrier(0);
  BAR();

  #pragma unroll
  for (int t = 0; t < 16; ++t) {
    if (t + 2 < 16) { stA(t + 2); stB(t + 2); }   // issue-early, 2 tiles ahead
    const u16* abase = lds + (t % 3) * 16384;
    const u16* bbase = lds + 49152 + (t % 3) * 8192;
    short8 af[2][4], bf[2][4];
    #pragma unroll
    for (int kk = 0; kk < 2; ++kk) {
      #pragma unroll
      for (int m = 0; m < 4; ++m) {
        const int lr = wm * 64 + m * 16 + l15;
        af[kk][m] = *(const short8*)(abase + lr * 64 + (((kk * 4 + l4) ^ (lr & 7)) << 3));
      }
      #pragma unroll
      for (int n = 0; n < 4; ++n) {
        const int lr = wn * 64 + n * 16 + l15;
        bf[kk][n] = *(const short8*)(bbase + lr * 64 + (((kk * 4 + l4) ^ (lr & 7)) << 3));
      }
    }
    LGKM0();
    SP1();
    #pragma unroll
    for (int kk = 0; kk < 2; ++kk)
      #pragma unroll
      for (int m = 0; m < 4; ++m)
        #pragma unroll
        for (int n = 0; n < 4; ++n)
          acc[m][n] = __builtin_amdgcn_mfma_f32_16x16x32_bf16(af[kk][m], bf[kk][n], acc[m][n], 0, 0, 0);
    SP0();
    // counted gate: drain stages of step t-1 (tile t+1) before next step reads it
    if (t <= 13)      asm volatile("s_waitcnt vmcnt(6)" ::: "memory");
    else if (t == 14) asm volatile("s_waitcnt vmcnt(0)" ::: "memory");
    __builtin_amdgcn_sched_barrier(0);
    BAR();
  }

  // ---- epilogue: z-dispatched fused stores ----
  const int gcol = n0 + wn * 64;                 // wave = one head's 64 cols
  const int z = gcol >> 10;                      // block-uniform
  const int hh = (gcol >> 6) & (NH - 1);
  const int mcol = gcol & (D_DIM - 1);
  const int rbase = m0 + wm * 64 + l4 * 4;
  const float lgh = log2f(1.f - exp2f(-5.f - (float)hh));   // log2(gamma_h) < 0

  if (z <= 1) {
    u16* dst = z ? kb : qb;
    const float slg  = z ? -lgh : lgh;
    const float base = z ? 1.f : 0.125f;
    #pragma unroll
    for (int m = 0; m < 4; ++m) {
      float o1v[2][4], o2v[2][4];
      #pragma unroll
      for (int r = 0; r < 4; ++r) {
        const int row = rbase + m * 16 + r;
        const int s = row & (S_LEN - 1);
        const float sc = base * exp2f((float)(s & 63) * slg);
        #pragma unroll
        for (int n = 0; n < 2; ++n) {
          const int dh0 = n * 16 + l15;          // 0..31
          const float2 cs = rope[s * 32 + dh0];
          const float x1 = acc[m][n][r], x2 = acc[m][n + 2][r];
          const float o1 = (x1 * cs.x - x2 * cs.y) * sc;
          const float o2 = (x2 * cs.x + x1 * cs.y) * sc;
          dst[(size_t)row * D_DIM + mcol + n * 16 + l15]       = f2bf(o1);
          dst[(size_t)row * D_DIM + mcol + (n + 2) * 16 + l15] = f2bf(o2);
          o1v[n][r] = o1; o2v[n][r] = o2;
        }
      }
      if (z == 1) {
        const int row0 = rbase + m * 16;
        const int bb = row0 >> 11, sr = row0 & (S_LEN - 1);
        #pragma unroll
        for (int n = 0; n < 2; ++n) {
          const int dh0 = n * 16 + l15;
          const uint2 p1 = make_uint2(pack_bf2(o1v[n][0], o1v[n][1]), pack_bf2(o1v[n][2], o1v[n][3]));
          const uint2 p2 = make_uint2(pack_bf2(o2v[n][0], o2v[n][1]), pack_bf2(o2v[n][2], o2v[n][3]));
          *(uint2*)(kT + (size_t)((bb * NH + hh) * DH + dh0) * S_LEN + sr)      = p1;
          *(uint2*)(kT + (size_t)((bb * NH + hh) * DH + dh0 + 32) * S_LEN + sr) = p2;
        }
      }
    }
  } else if (z == 2) {
    #pragma unroll
    for (int m = 0; m < 4; ++m) {
      const int row0 = rbase + m * 16;
      const int bb = row0 >> 11, sr = row0 & (S_LEN - 1);
      #pragma unroll
      for (int n = 0; n < 4; ++n) {
        const int dh = n * 16 + l15;
        const uint2 p = make_uint2(pack_bf2(acc[m][n][0], acc[m][n][1]),
                                   pack_bf2(acc[m][n][2], acc[m][n][3]));
        *(uint2*)(vT + (size_t)((bb * NH + hh) * DH + dh) * S_LEN + sr) = p;
      }
    }
  } else {
    #pragma unroll
    for (int m = 0; m < 4; ++m)
      #pragma unroll
      for (int n = 0; n < 4; ++n)
        #pragma unroll
        for (int r = 0; r < 4; ++r) {
          const int row = rbase + m * 16 + r;
          const float v = acc[m][n][r];
          gb[(size_t)row * D_DIM + mcol + n * 16 + l15] = f2bf(v / (1.f + __expf(-v)));
        }
  }
}

// ---------- ring-4 BK32 GEMM core (final_kernel) ----------
template<int BM, int BN, int WPM, int WPN>
__device__ __forceinline__ void gemm_bk32(const u16* __restrict__ A,
                                          const u16* __restrict__ W,
                                          const int m0, const int n0,
                                          u16* lds,
                                          f32x4 (&acc)[BM / (WPM * 16)][BN / (WPN * 16)])
{
  constexpr int T   = WPM * WPN * 64;
  constexpr int MR  = BM / (WPM * 16);
  constexpr int NR  = BN / (WPN * 16);
  constexpr int ALD = BM * 32;
  constexpr int BLD = BN * 32;
  constexpr int BUF = ALD + BLD;
  constexpr int NK  = D_DIM / 32;

  const int tid  = threadIdx.x;
  const int lane = tid & 63, wid = tid >> 6;
  const int wm = wid / WPN, wn = wid % WPN;
  const int l15 = lane & 15, l4 = lane >> 4;

  #pragma unroll
  for (int m = 0; m < MR; ++m)
    #pragma unroll
    for (int n = 0; n < NR; ++n)
      acc[m][n] = (f32x4){0.f, 0.f, 0.f, 0.f};

  auto stage = [&](int kt) {
    const int k0 = kt * 32;
    u16* la = lds + (kt & 3) * BUF;
    u16* lb = la + ALD;
    #pragma unroll
    for (int j = 0; j < BM * 4 / T; ++j) {
      const int c = tid + j * T;
      gll16(A + (size_t)(m0 + (c >> 2)) * D_DIM + k0 + (c & 3) * 8, la + c * 8);
    }
    #pragma unroll
    for (int j = 0; j < BN * 4 / T; ++j) {
      const int c = tid + j * T;
      gll16(W + (size_t)(n0 + (c >> 2)) * D_DIM + k0 + (c & 3) * 8, lb + c * 8);
    }
  };

  stage(0);
  stage(1);
  asm volatile("s_waitcnt vmcnt(4)" ::: "memory");
  BAR();
  __builtin_amdgcn_sched_barrier(0);

  for (int i = 0; i < NK; ++i) {
    if (i + 2 < NK) stage(i + 2);
    const u16* la = lds + (i & 3) * BUF + (wm * (BM / WPM) + l15) * 32 + l4 * 8;
    const u16* lb = lds + (i & 3) * BUF + ALD + (wn * (BN / WPN) + l15) * 32 + l4 * 8;
    short8 av[MR], bv[NR];
    #pragma unroll
    for (int m = 0; m < MR; ++m) av[m] = *(const short8*)(la + m * 16 * 32);
    #pragma unroll
    for (int n = 0; n < NR; ++n) bv[n] = *(const short8*)(lb + n * 16 * 32);
    SP1();
    #pragma unroll
    for (int m = 0; m < MR; ++m)
      #pragma unroll
      for (int n = 0; n < NR; ++n)
        acc[m][n] = __builtin_amdgcn_mfma_f32_16x16x32_bf16(av[m], bv[n], acc[m][n], 0, 0, 0);
    SP0();
    if (i + 2 < NK) asm volatile("s_waitcnt vmcnt(4)" ::: "memory");
    else            asm volatile("s_waitcnt vmcnt(0)" ::: "memory");
    BAR();
    __builtin_amdgcn_sched_barrier(0);
  }
}

// ---------- phase A: per-chunk outer product  At[bh][c][d2][d1] = (K-hat^T V)^T ----------
__global__ __launch_bounds__(256) void chunk_accum(
    const u16* __restrict__ kT, const u16* __restrict__ vT,
    u16* __restrict__ At)
{
  const int tid = threadIdx.x, lane = tid & 63, w = tid >> 6;
  const int l15 = lane & 15, l4 = lane >> 4;
  const int bh = blockIdx.x >> 5, c = blockIdx.x & 31;

  short8 a[2], bfr[2][4];
  #pragma unroll
  for (int kk = 0; kk < 2; ++kk) {
    a[kk] = *(const short8*)(vT + (size_t)(bh * DH + w * 16 + l15) * S_LEN + c * 64 + kk * 32 + l4 * 8);
    #pragma unroll
    for (int n = 0; n < 4; ++n)
      bfr[kk][n] = *(const short8*)(kT + (size_t)(bh * DH + n * 16 + l15) * S_LEN + c * 64 + kk * 32 + l4 * 8);
  }
  f32x4 acc[4];
  #pragma unroll
  for (int n = 0; n < 4; ++n) acc[n] = (f32x4){0.f, 0.f, 0.f, 0.f};
  #pragma unroll
  for (int kk = 0; kk < 2; ++kk)
    #pragma unroll
    for (int n = 0; n < 4; ++n)
      acc[n] = __builtin_amdgcn_mfma_f32_16x16x32_bf16(a[kk], bfr[kk][n], acc[n], 0, 0, 0);

  u16* dst = At + ((size_t)(bh * NCHUNK + c)) * 4096;
  #pragma unroll
  for (int n = 0; n < 4; ++n)
    #pragma unroll
    for (int r = 0; r < 4; ++r)
      dst[(w * 16 + l4 * 4 + r) * 64 + n * 16 + l15] = f2bf(acc[n][r]);
}

// ---------- phase B: elementwise scan over chunks ----------
__global__ __launch_bounds__(256) void chunk_scan(
    const u16* __restrict__ At, u16* __restrict__ St)
{
  const int gid = blockIdx.x * 256 + threadIdx.x;   // 32 bh * 4096 elems
  const int bh = gid >> 12, e = gid & 4095;
  const int h = bh & (NH - 1);
  const float lg = log2f(1.f - exp2f(-5.f - (float)h));
  const float gC = exp2f(64.f * lg);
  const u16* src = At + (size_t)bh * NCHUNK * 4096 + e;
  u16* dst = St + (size_t)bh * NCHUNK * 4096 + e;
  float s = 0.f;
  for (int c = 0; c < NCHUNK; ++c) {
    const float a = bf2f(src[(size_t)c * 4096]);
    dst[(size_t)c * 4096] = f2bf(s);
    s = gC * (s + a);
  }
}

// ---------- phase C: O = (masked Q~K^^T) V + Q~ State, fused * g ----------
__global__ __launch_bounds__(256) void chunk_out(
    const u16* __restrict__ qb, const u16* __restrict__ kb,
    const u16* __restrict__ vT, const u16* __restrict__ St,
    const u16* __restrict__ gb, u16* __restrict__ ob)
{
  __shared__ u16 Ps[4][16 * 64];   // 2 KB per wave, XOR-swizzled

  const int tid = threadIdx.x, lane = tid & 63, w = tid >> 6;
  const int l15 = lane & 15, l4 = lane >> 4;
  const int bh = blockIdx.x >> 5, c = blockIdx.x & 31;
  const int b = bh >> 4, h = bh & (NH - 1);
  const int q0 = c * 64 + w * 16;

  short8 qfr[2], kf[2][4], vf[2][4], sf[2][4];
  #pragma unroll
  for (int kk = 0; kk < 2; ++kk) {
    qfr[kk] = *(const short8*)(qb + (size_t)(b * S_LEN + q0 + l15) * D_DIM + h * DH + kk * 32 + l4 * 8);
    #pragma unroll
    for (int t = 0; t < 4; ++t)
      kf[kk][t] = *(const short8*)(kb + (size_t)(b * S_LEN + c * 64 + t * 16 + l15) * D_DIM + h * DH + kk * 32 + l4 * 8);
    #pragma unroll
    for (int n = 0; n < 4; ++n) {
      vf[kk][n] = *(const short8*)(vT + (size_t)(bh * DH + n * 16 + l15) * S_LEN + c * 64 + kk * 32 + l4 * 8);
      sf[kk][n] = *(const short8*)(St + ((size_t)(bh * NCHUNK + c)) * 4096 + (n * 16 + l15) * 64 + kk * 32 + l4 * 8);
    }
  }

  // S^T = mfma(K^, Q~)
  f32x4 st[4];
  #pragma unroll
  for (int tf = 0; tf < 4; ++tf) st[tf] = (f32x4){0.f, 0.f, 0.f, 0.f};
  #pragma unroll
  for (int kk = 0; kk < 2; ++kk)
    #pragma unroll
    for (int tf = 0; tf < 4; ++tf)
      st[tf] = __builtin_amdgcn_mfma_f32_16x16x32_bf16(kf[kk][tf], qfr[kk], st[tf], 0, 0, 0);

  // cross term: acc = Q~ StateT
  f32x4 acc[4];
  #pragma unroll
  for (int n = 0; n < 4; ++n) acc[n] = (f32x4){0.f, 0.f, 0.f, 0.f};
  #pragma unroll
  for (int kk = 0; kk < 2; ++kk)
    #pragma unroll
    for (int n = 0; n < 4; ++n)
      acc[n] = __builtin_amdgcn_mfma_f32_16x16x32_bf16(qfr[kk], sf[kk][n], acc[n], 0, 0, 0);

  // mask (t' <= q'), pack, swizzled per-wave LDS write
  u16* const psw = &Ps[w][0];
  const int qq = w * 16 + l15;
  #pragma unroll
  for (int tf = 0; tf < 4; ++tf) {
    const int tb = tf * 16 + l4 * 4;
    const float v0 = (tb + 0 <= qq) ? st[tf][0] : 0.f;
    const float v1 = (tb + 1 <= qq) ? st[tf][1] : 0.f;
    const float v2 = (tb + 2 <= qq) ? st[tf][2] : 0.f;
    const float v3 = (tb + 3 <= qq) ? st[tf][3] : 0.f;
    const uint2 u = make_uint2(pack_bf2(v0, v1), pack_bf2(v2, v3));
    const int boff = l15 * 128 + ((tf * 32 + l4 * 8) ^ ((l15 & 7) << 4));
    *(uint2*)((char*)psw + boff) = u;
  }

  // O += P V
  #pragma unroll
  for (int kk = 0; kk < 2; ++kk) {
    const int boff = l15 * 128 + ((kk * 64 + l4 * 16) ^ ((l15 & 7) << 4));
    const short8 pa = *(const short8*)((const char*)psw + boff);
    #pragma unroll
    for (int n = 0; n < 4; ++n)
      acc[n] = __builtin_amdgcn_mfma_f32_16x16x32_bf16(pa, vf[kk][n], acc[n], 0, 0, 0);
  }

  #pragma unroll
  for (int n = 0; n < 4; ++n)
    #pragma unroll
    for (int r = 0; r < 4; ++r) {
      const size_t idx = (size_t)(b * S_LEN + q0 + l4 * 4 + r) * D_DIM + h * DH + n * 16 + l15;
      ob[idx] = f2bf(acc[n][r] * bf2f(gb[idx]));
    }
}

// ---------- final GEMM: out = (O .* g) @ wo^T, fp32 output ----------
__global__ __launch_bounds__(256, 2) void final_kernel(
    const u16* __restrict__ ob, const u16* __restrict__ wob,
    float* __restrict__ out)
{
  __shared__ u16 lds[4 * (128 * 32 + 128 * 32)];   // 64 KB ring
  f32x4 acc[4][4];
  const int bid = blockIdx.x;                      // 256 blocks
  const int sw = (bid & 7) * 32 + (bid >> 3);      // XCD swizzle
  const int n0 = (sw & 7) * 128;
  const int m0 = (sw >> 3) * 128;
  gemm_bk32<128, 128, 2, 2>(ob, wob, m0, n0, lds, acc);

  const int lane = threadIdx.x & 63, wid = threadIdx.x >> 6;
  const int wm = wid >> 1, wn = wid & 1;
  const int rbase = m0 + wm * 64 + (lane >> 4) * 4;
  const int cbase = n0 + wn * 64 + (lane & 15);
  #pragma unroll
  for (int m = 0; m < 4; ++m)
    #pragma unroll
    for (int n = 0; n < 4; ++n)
      #pragma unroll
      for (int r = 0; r < 4; ++r)
        out[(size_t)(rbase + m * 16 + r) * D_DIM + cbase + n * 16] = acc[m][n][r];
}

extern "C" void kernel_launch(void* const* d_in, const int* in_sizes, int n_in,
                              void* d_out, int out_size, void* d_ws, size_t ws_size,
                              hipStream_t stream) {
  (void)in_sizes; (void)n_in; (void)out_size; (void)ws_size;
  const float* x  = (const float*)d_in[0];
  const float* wq = (const float*)d_in[1];
  const float* wk = (const float*)d_in[2];
  const float* wv = (const float*)d_in[3];
  const float* wg = (const float*)d_in[4];
  const float* wo = (const float*)d_in[5];
  float* out = (float*)d_out;

  char* ws = (char*)d_ws;
  const size_t SZ_X = (size_t)M_ROWS * D_DIM * 2;   // 8 MB
  const size_t SZ_W = (size_t)D_DIM * D_DIM * 2;    // 2 MB
  // [0..8)   xb            -> St  (state scan, alias after proj)
  // [8..16)  wcat[0..4)    -> At  (chunk products, alias after proj)
  // [16..18) wob = wcat[4] (live until final_kernel)
  // [18..26) qb  [26..34) kb  [34..42) vT  [42..50) gb
  // [50..58) kT            -> ob  (kT dead after chunk_accum)
  // [58..58.5) rope
  u16* xb   = (u16*)(ws);
  u16* wcat = (u16*)(ws + SZ_X);
  u16* wob  = (u16*)(ws + SZ_X + 4 * SZ_W);
  u16* qb   = (u16*)(ws + 1 * SZ_X + 5 * SZ_W);
  u16* kb   = (u16*)(ws + 2 * SZ_X + 5 * SZ_W);
  u16* vT   = (u16*)(ws + 3 * SZ_X + 5 * SZ_W);
  u16* gb   = (u16*)(ws + 4 * SZ_X + 5 * SZ_W);
  u16* kT   = (u16*)(ws + 5 * SZ_X + 5 * SZ_W);
  u16* ob   = kT;                                   // alias: kT dead after chunk_accum
  float2* rope = (float2*)(ws + 6 * SZ_X + 5 * SZ_W);
  u16* St   = (u16*)(ws);                           // alias: xb dead after proj
  u16* At   = (u16*)(ws + SZ_X);                    // alias: wcat dead after proj

  prep_kernel<<<dim3(9472), 256, 0, stream>>>(x, wq, wk, wv, wg, wo, xb, wcat, rope);

  proj_kernel<<<dim3(512), 512, 0, stream>>>(xb, wcat, qb, kb, kT, vT, gb, rope);

  chunk_accum<<<dim3(B_SZ * NH * NCHUNK), 256, 0, stream>>>(kT, vT, At);
  chunk_scan<<<dim3(B_SZ * NH * 4096 / 256), 256, 0, stream>>>(At, St);
  chunk_out<<<dim3(B_SZ * NH * NCHUNK), 256, 0, stream>>>(qb, kb, vT, St, gb, ob);

  final_kernel<<<dim3(256), 256, 0, stream>>>(ob, wob, out);
}

// Round 10
// 101.918 us; speedup vs baseline: 1.0957x; 1.0957x over previous
//
#include <hip/hip_runtime.h>
#include <hip/hip_bf16.h>

typedef unsigned short u16;
typedef unsigned int u32;
typedef __attribute__((ext_vector_type(8))) short short8;
typedef __attribute__((ext_vector_type(4))) float f32x4;

#define S_LEN 2048
#define D_DIM 1024
#define NH    16
#define DH    64
#define B_SZ  2
#define M_ROWS (B_SZ * S_LEN)   // 4096
#define NCHUNK (S_LEN / 64)     // 32 chunks of 64 rows

// ---------- helpers ----------
__device__ __forceinline__ u16 f2bf(float f) {
  u32 u = __float_as_uint(f);
  u += 0x7FFFu + ((u >> 16) & 1u);   // RNE
  return (u16)(u >> 16);
}
__device__ __forceinline__ float bf2f(u16 u) {
  return __uint_as_float(((u32)u) << 16);
}
__device__ __forceinline__ u32 pack_bf2(float lo, float hi) {
  __hip_bfloat162 p = __float22bfloat162_rn(make_float2(lo, hi));  // v_cvt_pk_bf16_f32
  u32 r;
  __builtin_memcpy(&r, &p, 4);
  return r;
}

__device__ __forceinline__ void gll16(const void* g, void* l) {
  __builtin_amdgcn_global_load_lds((const __attribute__((address_space(1))) u32*)g,
                                   (__attribute__((address_space(3))) u32*)l,
                                   16, 0, 0);
}

#define SP1() __builtin_amdgcn_s_setprio(1)
#define SP0() __builtin_amdgcn_s_setprio(0)
#define BAR() __builtin_amdgcn_s_barrier()
#define LGKM0() do { asm volatile("s_waitcnt lgkmcnt(0)" ::: "memory"); \
                     __builtin_amdgcn_sched_barrier(0); } while (0)

// ---------- fused prep: x->bf16, 5 weights->wcat bf16, rope table ----------
__global__ __launch_bounds__(256) void prep_kernel(
    const float* __restrict__ x,
    const float* __restrict__ wq, const float* __restrict__ wk,
    const float* __restrict__ wv, const float* __restrict__ wg,
    const float* __restrict__ wo,
    u16* __restrict__ xb, u16* __restrict__ wcat, float2* __restrict__ rope)
{
  const int bid = blockIdx.x, tid = threadIdx.x;
  if (bid < 4096) {                      // x: 4096*1024 elems / 4 = 1048576 float4
    const int i = bid * 256 + tid;
    const float4 v = ((const float4*)x)[i];
    u32* d = (u32*)xb;
    d[2 * i]     = (u32)f2bf(v.x) | ((u32)f2bf(v.y) << 16);
    d[2 * i + 1] = (u32)f2bf(v.z) | ((u32)f2bf(v.w) << 16);
  } else if (bid < 9216) {               // 5 weights, 1024 blocks each
    const int t = bid - 4096;
    const int seg = t >> 10;
    const float* src = seg == 0 ? wq : seg == 1 ? wk : seg == 2 ? wv : seg == 3 ? wg : wo;
    const int i = (t & 1023) * 256 + tid;
    const float4 v = ((const float4*)src)[i];
    u32* d = (u32*)(wcat + (size_t)seg * D_DIM * D_DIM);
    d[2 * i]     = (u32)f2bf(v.x) | ((u32)f2bf(v.y) << 16);
    d[2 * i + 1] = (u32)f2bf(v.z) | ((u32)f2bf(v.w) << 16);
  } else {                               // rope: S_LEN*32 entries, 256 blocks
    const int i = (bid - 9216) * 256 + tid;
    const int s = i >> 5, j = i & 31;
    float inv = exp2f(-(float)j * (13.287712379549449f / 32.f)); // 10000^(-j/32)
    float fr = (float)s * inv;
    rope[i] = make_float2(cosf(fr), sinf(fr));
  }
}

// ---------- 4-phase 256x256 proj GEMM + fused epilogues ----------
// z = col>>10: 0=q(+rope,*0.125*gamma^(s&63)), 1=k(+rope,*gamma^-(s&63), +kT),
// 2=v(->vT transposed), 3=g(silu)
__global__ __launch_bounds__(512, 2) void proj_kernel(
    const u16* __restrict__ xb, const u16* __restrict__ wcat,
    u16* __restrict__ qb, u16* __restrict__ kb, u16* __restrict__ kT,
    u16* __restrict__ vT, u16* __restrict__ gb,
    const float2* __restrict__ rope)
{
  // 128 KB: A halves [buf][h] at ((buf*2+h)*8192), B at 32768 + same
  __shared__ u16 lds[65536];
  const int tid = threadIdx.x, lane = tid & 63, wid = tid >> 6;
  const int wm = wid >> 2, wn = wid & 3;
  const int l15 = lane & 15, l4 = lane >> 4;

  // L2-capacity-fit XCD mapping: 16 regions of 4m x 4n 256-tiles (4 MB working
  // set = per-XCD L2); 2 regions per XCD, bijective.
  const int bid = blockIdx.x;                     // 256 blocks
  const int xcd = bid & 7, idx = bid >> 3;        // 32 blocks per XCD
  const int rgn = xcd + 8 * (idx >> 4);           // 0..15
  const int cell = idx & 15;
  const int m0 = ((rgn & 3) * 4 + (cell & 3)) * 256;
  const int n0 = ((rgn >> 2) * 4 + (cell >> 2)) * 256;

  f32x4 acc[8][4];
  #pragma unroll
  for (int m = 0; m < 8; ++m)
    #pragma unroll
    for (int n = 0; n < 4; ++n)
      acc[m][n] = (f32x4){0.f, 0.f, 0.f, 0.f};

  short8 a[4][2], b0[2][2], b1[2][2];

  // stage one half-tile (128 rows x 64 k-cols): 2 gll16 per thread,
  // pre-swizzled global source + linear LDS (rule 21)
  auto stA = [&](int t, int h) {
    u16* dst = lds + ((t & 1) * 2 + h) * 8192;
    const u16* src = xb + (size_t)(m0 + h * 128) * D_DIM + t * 64;
    #pragma unroll
    for (int j = 0; j < 2; ++j) {
      const int c = tid + j * 512, row = c >> 3, ch = c & 7;
      gll16(src + (size_t)row * D_DIM + ((ch ^ (row & 7)) << 3), dst + c * 8);
    }
  };
  auto stB = [&](int t, int h) {
    u16* dst = lds + 32768 + ((t & 1) * 2 + h) * 8192;
    const u16* src = wcat + (size_t)(n0 + h * 128) * D_DIM + t * 64;
    #pragma unroll
    for (int j = 0; j < 2; ++j) {
      const int c = tid + j * 512, row = c >> 3, ch = c & 7;
      gll16(src + (size_t)row * D_DIM + ((ch ^ (row & 7)) << 3), dst + c * 8);
    }
  };
  // fragment loads (swizzled read side)
  auto ldA = [&](int d, int mh) {
    const u16* base = lds + (d * 2 + wm) * 8192;
    #pragma unroll
    for (int m = 0; m < 4; ++m) {
      const int lr = mh * 64 + m * 16 + l15;
      #pragma unroll
      for (int kk = 0; kk < 2; ++kk)
        a[m][kk] = *(const short8*)(base + lr * 64 + (((kk * 4 + l4) ^ (lr & 7)) << 3));
    }
  };
  auto ldB = [&](short8 (&b)[2][2], int d, int nh) {
    const u16* base = lds + 32768 + (d * 2 + (wn >> 1)) * 8192;
    #pragma unroll
    for (int j = 0; j < 2; ++j) {
      const int lr = (wn & 1) * 64 + (nh * 2 + j) * 16 + l15;
      #pragma unroll
      for (int kk = 0; kk < 2; ++kk)
        b[j][kk] = *(const short8*)(base + lr * 64 + (((kk * 4 + l4) ^ (lr & 7)) << 3));
    }
  };
  auto quad = [&](int mh, int nh, short8 (&b)[2][2]) {
    #pragma unroll
    for (int m = 0; m < 4; ++m)
      #pragma unroll
      for (int j = 0; j < 2; ++j)
        #pragma unroll
        for (int kk = 0; kk < 2; ++kk)
          acc[mh * 4 + m][nh * 2 + j] =
              __builtin_amdgcn_mfma_f32_16x16x32_bf16(a[m][kk], b[j][kk],
                                                      acc[mh * 4 + m][nh * 2 + j], 0, 0, 0);
  };

  // prologue: tile0 (all 4 halves) + B(1,h0/h1); A(1,*) staged at PhA
  stB(0, 0); stA(0, 0); stB(0, 1); stA(0, 1); stB(1, 0); stB(1, 1);
  asm volatile("s_waitcnt vmcnt(4)" ::: "memory");   // tile0's 4 halves landed
  BAR();

  // 4 merged phases per iteration (2 K-tiles), 8 barriers/iter.
  // Stage schedule per iter i (tiles t1=2i+1, t2=2i+2, t3=2i+3):
  //   PhA: A(t1,h0) A(t1,h1)   PhB: B(t2,h0) A(t2,h0)
  //   PhC: B(t2,h1) A(t2,h1)   PhD: B(t3,h0) B(t3,h1)
  // vmcnt(4) at PhB/PhD-end: newest 4 gll16 outstanding, older tiles landed.
  for (int i = 0; i < 8; ++i) {
    const int t1 = 2 * i + 1, t2 = 2 * i + 2, t3 = 2 * i + 3;
    // ---- PhA: buf0, quads (0,0)+(0,1) ----
    ldA(0, 0); ldB(b0, 0, 0); ldB(b1, 0, 1);
    stA(t1, 0); stA(t1, 1);
    asm volatile("s_waitcnt lgkmcnt(8)" ::: "memory");
    BAR(); LGKM0();
    SP1(); quad(0, 0, b0); quad(0, 1, b1); SP0();
    BAR();
    // ---- PhB: buf0, quads (1,0)+(1,1) ----
    ldA(0, 1);
    if (t2 < 16) { stB(t2, 0); stA(t2, 0); }
    asm volatile("s_waitcnt lgkmcnt(4)" ::: "memory");
    BAR(); LGKM0();
    SP1(); quad(1, 0, b0); quad(1, 1, b1); SP0();
    if (i == 7) asm volatile("s_waitcnt vmcnt(0)" ::: "memory");
    else        asm volatile("s_waitcnt vmcnt(4)" ::: "memory");
    BAR();
    // ---- PhC: buf1, quads (0,0)+(0,1) ----
    ldA(1, 0); ldB(b0, 1, 0); ldB(b1, 1, 1);
    if (t2 < 16) { stB(t2, 1); stA(t2, 1); }
    asm volatile("s_waitcnt lgkmcnt(8)" ::: "memory");
    BAR(); LGKM0();
    SP1(); quad(0, 0, b0); quad(0, 1, b1); SP0();
    BAR();
    // ---- PhD: buf1, quads (1,0)+(1,1) ----
    ldA(1, 1);
    if (t3 < 16) { stB(t3, 0); stB(t3, 1); }
    asm volatile("s_waitcnt lgkmcnt(4)" ::: "memory");
    BAR(); LGKM0();
    SP1(); quad(1, 0, b0); quad(1, 1, b1); SP0();
    if (i < 7) asm volatile("s_waitcnt vmcnt(4)" ::: "memory");
    else       asm volatile("s_waitcnt vmcnt(0)" ::: "memory");
    BAR();
  }

  // ---- epilogue: z-dispatched fused stores ----
  const int gcol = n0 + wn * 64;                 // wave = one head's 64 cols
  const int z = gcol >> 10;                      // block-uniform
  const int hh = (gcol >> 6) & (NH - 1);
  const int mcol = gcol & (D_DIM - 1);
  const int rbase = m0 + wm * 128 + l4 * 4;
  const float lgh = log2f(1.f - exp2f(-5.f - (float)hh));   // log2(gamma_h) < 0

  if (z <= 1) {
    u16* dst = z ? kb : qb;
    const float slg  = z ? -lgh : lgh;
    const float base = z ? 1.f : 0.125f;
    #pragma unroll
    for (int m = 0; m < 8; ++m) {
      float o1v[2][4], o2v[2][4];
      #pragma unroll
      for (int r = 0; r < 4; ++r) {
        const int row = rbase + m * 16 + r;
        const int s = row & (S_LEN - 1);
        const float sc = base * exp2f((float)(s & 63) * slg);
        #pragma unroll
        for (int n = 0; n < 2; ++n) {
          const int dh0 = n * 16 + l15;          // 0..31
          const float2 cs = rope[s * 32 + dh0];
          const float x1 = acc[m][n][r], x2 = acc[m][n + 2][r];
          const float o1 = (x1 * cs.x - x2 * cs.y) * sc;
          const float o2 = (x2 * cs.x + x1 * cs.y) * sc;
          dst[(size_t)row * D_DIM + mcol + n * 16 + l15]       = f2bf(o1);
          dst[(size_t)row * D_DIM + mcol + (n + 2) * 16 + l15] = f2bf(o2);
          o1v[n][r] = o1; o2v[n][r] = o2;
        }
      }
      if (z == 1) {
        const int row0 = rbase + m * 16;
        const int bb = row0 >> 11, sr = row0 & (S_LEN - 1);
        #pragma unroll
        for (int n = 0; n < 2; ++n) {
          const int dh0 = n * 16 + l15;
          const uint2 p1 = make_uint2(pack_bf2(o1v[n][0], o1v[n][1]), pack_bf2(o1v[n][2], o1v[n][3]));
          const uint2 p2 = make_uint2(pack_bf2(o2v[n][0], o2v[n][1]), pack_bf2(o2v[n][2], o2v[n][3]));
          *(uint2*)(kT + (size_t)((bb * NH + hh) * DH + dh0) * S_LEN + sr)      = p1;
          *(uint2*)(kT + (size_t)((bb * NH + hh) * DH + dh0 + 32) * S_LEN + sr) = p2;
        }
      }
    }
  } else if (z == 2) {
    #pragma unroll
    for (int m = 0; m < 8; ++m) {
      const int row0 = rbase + m * 16;
      const int bb = row0 >> 11, sr = row0 & (S_LEN - 1);
      #pragma unroll
      for (int n = 0; n < 4; ++n) {
        const int dh = n * 16 + l15;
        const uint2 p = make_uint2(pack_bf2(acc[m][n][0], acc[m][n][1]),
                                   pack_bf2(acc[m][n][2], acc[m][n][3]));
        *(uint2*)(vT + (size_t)((bb * NH + hh) * DH + dh) * S_LEN + sr) = p;
      }
    }
  } else {
    #pragma unroll
    for (int m = 0; m < 8; ++m)
      #pragma unroll
      for (int n = 0; n < 4; ++n)
        #pragma unroll
        for (int r = 0; r < 4; ++r) {
          const int row = rbase + m * 16 + r;
          const float v = acc[m][n][r];
          gb[(size_t)row * D_DIM + mcol + n * 16 + l15] = f2bf(v / (1.f + __expf(-v)));
        }
  }
}

// ---------- ring-4 BK32 GEMM core (final_kernel) ----------
template<int BM, int BN, int WPM, int WPN>
__device__ __forceinline__ void gemm_bk32(const u16* __restrict__ A,
                                          const u16* __restrict__ W,
                                          const int m0, const int n0,
                                          u16* lds,
                                          f32x4 (&acc)[BM / (WPM * 16)][BN / (WPN * 16)])
{
  constexpr int T   = WPM * WPN * 64;
  constexpr int MR  = BM / (WPM * 16);
  constexpr int NR  = BN / (WPN * 16);
  constexpr int ALD = BM * 32;
  constexpr int BLD = BN * 32;
  constexpr int BUF = ALD + BLD;
  constexpr int NK  = D_DIM / 32;

  const int tid  = threadIdx.x;
  const int lane = tid & 63, wid = tid >> 6;
  const int wm = wid / WPN, wn = wid % WPN;
  const int l15 = lane & 15, l4 = lane >> 4;

  #pragma unroll
  for (int m = 0; m < MR; ++m)
    #pragma unroll
    for (int n = 0; n < NR; ++n)
      acc[m][n] = (f32x4){0.f, 0.f, 0.f, 0.f};

  auto stage = [&](int kt) {
    const int k0 = kt * 32;
    u16* la = lds + (kt & 3) * BUF;
    u16* lb = la + ALD;
    #pragma unroll
    for (int j = 0; j < BM * 4 / T; ++j) {
      const int c = tid + j * T;
      gll16(A + (size_t)(m0 + (c >> 2)) * D_DIM + k0 + (c & 3) * 8, la + c * 8);
    }
    #pragma unroll
    for (int j = 0; j < BN * 4 / T; ++j) {
      const int c = tid + j * T;
      gll16(W + (size_t)(n0 + (c >> 2)) * D_DIM + k0 + (c & 3) * 8, lb + c * 8);
    }
  };

  stage(0);
  stage(1);
  asm volatile("s_waitcnt vmcnt(4)" ::: "memory");
  BAR();
  __builtin_amdgcn_sched_barrier(0);

  for (int i = 0; i < NK; ++i) {
    if (i + 2 < NK) stage(i + 2);
    const u16* la = lds + (i & 3) * BUF + (wm * (BM / WPM) + l15) * 32 + l4 * 8;
    const u16* lb = lds + (i & 3) * BUF + ALD + (wn * (BN / WPN) + l15) * 32 + l4 * 8;
    short8 av[MR], bv[NR];
    #pragma unroll
    for (int m = 0; m < MR; ++m) av[m] = *(const short8*)(la + m * 16 * 32);
    #pragma unroll
    for (int n = 0; n < NR; ++n) bv[n] = *(const short8*)(lb + n * 16 * 32);
    SP1();
    #pragma unroll
    for (int m = 0; m < MR; ++m)
      #pragma unroll
      for (int n = 0; n < NR; ++n)
        acc[m][n] = __builtin_amdgcn_mfma_f32_16x16x32_bf16(av[m], bv[n], acc[m][n], 0, 0, 0);
    SP0();
    if (i + 2 < NK) asm volatile("s_waitcnt vmcnt(4)" ::: "memory");
    else            asm volatile("s_waitcnt vmcnt(0)" ::: "memory");
    BAR();
    __builtin_amdgcn_sched_barrier(0);
  }
}

// ---------- phase A: per-chunk outer product  At[bh][c][d2][d1] = (K-hat^T V)^T ----------
__global__ __launch_bounds__(256) void chunk_accum(
    const u16* __restrict__ kT, const u16* __restrict__ vT,
    u16* __restrict__ At)
{
  const int tid = threadIdx.x, lane = tid & 63, w = tid >> 6;
  const int l15 = lane & 15, l4 = lane >> 4;
  const int bh = blockIdx.x >> 5, c = blockIdx.x & 31;

  short8 a[2], bfr[2][4];
  #pragma unroll
  for (int kk = 0; kk < 2; ++kk) {
    a[kk] = *(const short8*)(vT + (size_t)(bh * DH + w * 16 + l15) * S_LEN + c * 64 + kk * 32 + l4 * 8);
    #pragma unroll
    for (int n = 0; n < 4; ++n)
      bfr[kk][n] = *(const short8*)(kT + (size_t)(bh * DH + n * 16 + l15) * S_LEN + c * 64 + kk * 32 + l4 * 8);
  }
  f32x4 acc[4];
  #pragma unroll
  for (int n = 0; n < 4; ++n) acc[n] = (f32x4){0.f, 0.f, 0.f, 0.f};
  #pragma unroll
  for (int kk = 0; kk < 2; ++kk)
    #pragma unroll
    for (int n = 0; n < 4; ++n)
      acc[n] = __builtin_amdgcn_mfma_f32_16x16x32_bf16(a[kk], bfr[kk][n], acc[n], 0, 0, 0);

  u16* dst = At + ((size_t)(bh * NCHUNK + c)) * 4096;
  #pragma unroll
  for (int n = 0; n < 4; ++n)
    #pragma unroll
    for (int r = 0; r < 4; ++r)
      dst[(w * 16 + l4 * 4 + r) * 64 + n * 16 + l15] = f2bf(acc[n][r]);
}

// ---------- phase B: elementwise scan over chunks ----------
__global__ __launch_bounds__(256) void chunk_scan(
    const u16* __restrict__ At, u16* __restrict__ St)
{
  const int gid = blockIdx.x * 256 + threadIdx.x;   // 32 bh * 4096 elems
  const int bh = gid >> 12, e = gid & 4095;
  const int h = bh & (NH - 1);
  const float lg = log2f(1.f - exp2f(-5.f - (float)h));
  const float gC = exp2f(64.f * lg);
  const u16* src = At + (size_t)bh * NCHUNK * 4096 + e;
  u16* dst = St + (size_t)bh * NCHUNK * 4096 + e;
  float s = 0.f;
  for (int c = 0; c < NCHUNK; ++c) {
    const float a = bf2f(src[(size_t)c * 4096]);
    dst[(size_t)c * 4096] = f2bf(s);
    s = gC * (s + a);
  }
}

// ---------- phase C: O = (masked Q~K^^T) V + Q~ State, fused * g ----------
__global__ __launch_bounds__(256) void chunk_out(
    const u16* __restrict__ qb, const u16* __restrict__ kb,
    const u16* __restrict__ vT, const u16* __restrict__ St,
    const u16* __restrict__ gb, u16* __restrict__ ob)
{
  __shared__ u16 Ps[4][16 * 64];   // 2 KB per wave, XOR-swizzled

  const int tid = threadIdx.x, lane = tid & 63, w = tid >> 6;
  const int l15 = lane & 15, l4 = lane >> 4;
  const int bh = blockIdx.x >> 5, c = blockIdx.x & 31;
  const int b = bh >> 4, h = bh & (NH - 1);
  const int q0 = c * 64 + w * 16;

  short8 qfr[2], kf[2][4], vf[2][4], sf[2][4];
  #pragma unroll
  for (int kk = 0; kk < 2; ++kk) {
    qfr[kk] = *(const short8*)(qb + (size_t)(b * S_LEN + q0 + l15) * D_DIM + h * DH + kk * 32 + l4 * 8);
    #pragma unroll
    for (int t = 0; t < 4; ++t)
      kf[kk][t] = *(const short8*)(kb + (size_t)(b * S_LEN + c * 64 + t * 16 + l15) * D_DIM + h * DH + kk * 32 + l4 * 8);
    #pragma unroll
    for (int n = 0; n < 4; ++n) {
      vf[kk][n] = *(const short8*)(vT + (size_t)(bh * DH + n * 16 + l15) * S_LEN + c * 64 + kk * 32 + l4 * 8);
      sf[kk][n] = *(const short8*)(St + ((size_t)(bh * NCHUNK + c)) * 4096 + (n * 16 + l15) * 64 + kk * 32 + l4 * 8);
    }
  }

  // S^T = mfma(K^, Q~)
  f32x4 st[4];
  #pragma unroll
  for (int tf = 0; tf < 4; ++tf) st[tf] = (f32x4){0.f, 0.f, 0.f, 0.f};
  #pragma unroll
  for (int kk = 0; kk < 2; ++kk)
    #pragma unroll
    for (int tf = 0; tf < 4; ++tf)
      st[tf] = __builtin_amdgcn_mfma_f32_16x16x32_bf16(kf[kk][tf], qfr[kk], st[tf], 0, 0, 0);

  // cross term: acc = Q~ StateT
  f32x4 acc[4];
  #pragma unroll
  for (int n = 0; n < 4; ++n) acc[n] = (f32x4){0.f, 0.f, 0.f, 0.f};
  #pragma unroll
  for (int kk = 0; kk < 2; ++kk)
    #pragma unroll
    for (int n = 0; n < 4; ++n)
      acc[n] = __builtin_amdgcn_mfma_f32_16x16x32_bf16(qfr[kk], sf[kk][n], acc[n], 0, 0, 0);

  // mask (t' <= q'), pack, swizzled per-wave LDS write
  u16* const psw = &Ps[w][0];
  const int qq = w * 16 + l15;
  #pragma unroll
  for (int tf = 0; tf < 4; ++tf) {
    const int tb = tf * 16 + l4 * 4;
    const float v0 = (tb + 0 <= qq) ? st[tf][0] : 0.f;
    const float v1 = (tb + 1 <= qq) ? st[tf][1] : 0.f;
    const float v2 = (tb + 2 <= qq) ? st[tf][2] : 0.f;
    const float v3 = (tb + 3 <= qq) ? st[tf][3] : 0.f;
    const uint2 u = make_uint2(pack_bf2(v0, v1), pack_bf2(v2, v3));
    const int boff = l15 * 128 + ((tf * 32 + l4 * 8) ^ ((l15 & 7) << 4));
    *(uint2*)((char*)psw + boff) = u;
  }

  // O += P V
  #pragma unroll
  for (int kk = 0; kk < 2; ++kk) {
    const int boff = l15 * 128 + ((kk * 64 + l4 * 16) ^ ((l15 & 7) << 4));
    const short8 pa = *(const short8*)((const char*)psw + boff);
    #pragma unroll
    for (int n = 0; n < 4; ++n)
      acc[n] = __builtin_amdgcn_mfma_f32_16x16x32_bf16(pa, vf[kk][n], acc[n], 0, 0, 0);
  }

  #pragma unroll
  for (int n = 0; n < 4; ++n)
    #pragma unroll
    for (int r = 0; r < 4; ++r) {
      const size_t idx = (size_t)(b * S_LEN + q0 + l4 * 4 + r) * D_DIM + h * DH + n * 16 + l15;
      ob[idx] = f2bf(acc[n][r] * bf2f(gb[idx]));
    }
}

// ---------- final GEMM: out = (O .* g) @ wo^T, fp32 output ----------
__global__ __launch_bounds__(256, 2) void final_kernel(
    const u16* __restrict__ ob, const u16* __restrict__ wob,
    float* __restrict__ out)
{
  __shared__ u16 lds[4 * (128 * 32 + 128 * 32)];   // 64 KB ring
  f32x4 acc[4][4];
  // L2-fit XCD mapping: each XCD owns an m-stripe of 4 (x all 8 n) -> 3 MB/XCD
  const int bid = blockIdx.x;                      // 256 blocks
  const int xcd = bid & 7, idx = bid >> 3;         // idx 0..31
  const int m0 = (xcd * 4 + (idx & 3)) * 128;
  const int n0 = (idx >> 2) * 128;
  gemm_bk32<128, 128, 2, 2>(ob, wob, m0, n0, lds, acc);

  const int lane = threadIdx.x & 63, wid = threadIdx.x >> 6;
  const int wm = wid >> 1, wn = wid & 1;
  const int rbase = m0 + wm * 64 + (lane >> 4) * 4;
  const int cbase = n0 + wn * 64 + (lane & 15);
  #pragma unroll
  for (int m = 0; m < 4; ++m)
    #pragma unroll
    for (int n = 0; n < 4; ++n)
      #pragma unroll
      for (int r = 0; r < 4; ++r)
        out[(size_t)(rbase + m * 16 + r) * D_DIM + cbase + n * 16] = acc[m][n][r];
}

extern "C" void kernel_launch(void* const* d_in, const int* in_sizes, int n_in,
                              void* d_out, int out_size, void* d_ws, size_t ws_size,
                              hipStream_t stream) {
  (void)in_sizes; (void)n_in; (void)out_size; (void)ws_size;
  const float* x  = (const float*)d_in[0];
  const float* wq = (const float*)d_in[1];
  const float* wk = (const float*)d_in[2];
  const float* wv = (const float*)d_in[3];
  const float* wg = (const float*)d_in[4];
  const float* wo = (const float*)d_in[5];
  float* out = (float*)d_out;

  char* ws = (char*)d_ws;
  const size_t SZ_X = (size_t)M_ROWS * D_DIM * 2;   // 8 MB
  const size_t SZ_W = (size_t)D_DIM * D_DIM * 2;    // 2 MB
  // [0..8)   xb            -> St  (state scan, alias after proj)
  // [8..16)  wcat[0..4)    -> At  (chunk products, alias after proj)
  // [16..18) wob = wcat[4] (live until final_kernel)
  // [18..26) qb  [26..34) kb  [34..42) vT  [42..50) gb
  // [50..58) kT            -> ob  (kT dead after chunk_accum)
  // [58..58.5) rope
  u16* xb   = (u16*)(ws);
  u16* wcat = (u16*)(ws + SZ_X);
  u16* wob  = (u16*)(ws + SZ_X + 4 * SZ_W);
  u16* qb   = (u16*)(ws + 1 * SZ_X + 5 * SZ_W);
  u16* kb   = (u16*)(ws + 2 * SZ_X + 5 * SZ_W);
  u16* vT   = (u16*)(ws + 3 * SZ_X + 5 * SZ_W);
  u16* gb   = (u16*)(ws + 4 * SZ_X + 5 * SZ_W);
  u16* kT   = (u16*)(ws + 5 * SZ_X + 5 * SZ_W);
  u16* ob   = kT;                                   // alias: kT dead after chunk_accum
  float2* rope = (float2*)(ws + 6 * SZ_X + 5 * SZ_W);
  u16* St   = (u16*)(ws);                           // alias: xb dead after proj
  u16* At   = (u16*)(ws + SZ_X);                    // alias: wcat dead after proj

  prep_kernel<<<dim3(9472), 256, 0, stream>>>(x, wq, wk, wv, wg, wo, xb, wcat, rope);

  proj_kernel<<<dim3(256), 512, 0, stream>>>(xb, wcat, qb, kb, kT, vT, gb, rope);

  chunk_accum<<<dim3(B_SZ * NH * NCHUNK), 256, 0, stream>>>(kT, vT, At);
  chunk_scan<<<dim3(B_SZ * NH * 4096 / 256), 256, 0, stream>>>(At, St);
  chunk_out<<<dim3(B_SZ * NH * NCHUNK), 256, 0, stream>>>(qb, kb, vT, St, gb, ob);

  final_kernel<<<dim3(256), 256, 0, stream>>>(ob, wob, out);
}